// Round 1
// baseline (258.338 us; speedup 1.0000x reference)
//
#include <hip/hip_runtime.h>
#include <stdint.h>

// Problem constants
#define BB   4
#define CCH  256
#define HH   64
#define WWD  64
#define HWSZ 4096          // H*W
#define DGRP 4
#define CG   64            // C / DG
#define KKN  9
#define KT   2304          // C * KK  (k index = kk*256 + c)
#define NND  16384         // B*H*W
#define GNG  32
#define EPSV 1e-5f

// Workspace layout (bytes):
//  colT  bf16 [NND][KT]            @ 0          size 75,497,472
//  Wb    bf16 [256][KT]            @ 75497472   size  1,179,648
//  G     f32  [256][NND]           @ 76677120   size 16,777,216
//  stats f32  [128][2] (mean,rstd) @ 93454336   size      1,024
#define WS_COLT  0
#define WS_WB    75497472
#define WS_G     76677120
#define WS_STATS 93454336

typedef __attribute__((ext_vector_type(8))) short short8;
typedef __attribute__((ext_vector_type(4))) float f32x4;

__device__ inline unsigned short f2bf(float f) {
    union { float f; unsigned u; } v; v.f = f;
    unsigned u = v.u;
    return (unsigned short)((u + 0x7FFFu + ((u >> 16) & 1u)) >> 16);  // RNE
}

__device__ inline void gl_lds16(const void* g, void* l) {
    __builtin_amdgcn_global_load_lds(
        (const __attribute__((address_space(1))) void*)g,
        (__attribute__((address_space(3))) void*)l,
        16, 0, 0);
}

// ---------------- Kernel 1: weight repack fp32 -> bf16, k = kk*256 + c ------
__global__ __launch_bounds__(256) void wconv_kernel(const float* __restrict__ wd,
                                                    unsigned short* __restrict__ Wb) {
    int idx = blockIdx.x * 256 + threadIdx.x;       // 589,824 total
    int o = idx / KT;
    int r = idx % KT;
    int kk = r >> 8;        // r / 256
    int c  = r & 255;
    Wb[idx] = f2bf(wd[o * KT + c * KKN + kk]);
}

// ---------------- Kernel 2: offsets + bilinear sampling -> colT bf16 --------
// thread = one (b, dg, kk, h, w); writes 64 channels (contiguous 128B in colT row)
__global__ __launch_bounds__(256) void col_kernel(const float* __restrict__ x,
                                                  const float* __restrict__ shp,
                                                  const float* __restrict__ woff,
                                                  unsigned short* __restrict__ colT) {
    int idx = blockIdx.x * 256 + threadIdx.x;       // 589,824 total
    int hw  = idx & 4095;
    int w   = idx & 63;
    int h   = (idx >> 6) & 63;
    int q   = idx >> 12;          // (b*4+dg)*9 + kk
    int kk  = q % KKN;
    int bdg = q / KKN;
    int dg  = bdg & 3;
    int b   = bdg >> 2;

    float s0 = shp[(b * 4 + 0) * HWSZ + hw];
    float s1 = shp[(b * 4 + 1) * HWSZ + hw];
    float s2 = shp[(b * 4 + 2) * HWSZ + hw];
    float s3 = shp[(b * 4 + 3) * HWSZ + hw];

    const float* wo = woff + (dg * 18 + kk * 2) * 4;   // rows o_y, o_x back-to-back
    float dy = wo[0] * s0 + wo[1] * s1 + wo[2] * s2 + wo[3] * s3;
    float dx = wo[4] * s0 + wo[5] * s1 + wo[6] * s2 + wo[7] * s3;

    int ky = kk / 3, kx = kk % 3;
    float y  = (float)(h - 1 + ky) + dy;
    float xs = (float)(w - 1 + kx) + dx;
    float y0f = floorf(y), x0f = floorf(xs);
    float wy1 = y - y0f,  wx1 = xs - x0f;
    float wy0 = 1.f - wy1, wx0 = 1.f - wx1;
    int iy0 = (int)y0f, ix0 = (int)x0f;
    int iy1 = iy0 + 1,  ix1 = ix0 + 1;
    bool vy0 = (iy0 >= 0) && (iy0 < HH);
    bool vy1 = (iy1 >= 0) && (iy1 < HH);
    bool vx0 = (ix0 >= 0) && (ix0 < WWD);
    bool vx1 = (ix1 >= 0) && (ix1 < WWD);
    float w00 = (vy0 && vx0) ? wy0 * wx0 : 0.f;
    float w01 = (vy0 && vx1) ? wy0 * wx1 : 0.f;
    float w10 = (vy1 && vx0) ? wy1 * wx0 : 0.f;
    float w11 = (vy1 && vx1) ? wy1 * wx1 : 0.f;
    int cy0 = min(max(iy0, 0), HH - 1);
    int cy1 = min(max(iy1, 0), HH - 1);
    int cx0 = min(max(ix0, 0), WWD - 1);
    int cx1 = min(max(ix1, 0), WWD - 1);
    int o00 = cy0 * WWD + cx0;
    int o01 = cy0 * WWD + cx1;
    int o10 = cy1 * WWD + cx0;
    int o11 = cy1 * WWD + cx1;

    const float* xb = x + (size_t)(b * CCH + dg * CG) * HWSZ;
    unsigned short* outp = colT + (size_t)(b * HWSZ + hw) * KT + kk * 256 + dg * CG;

    #pragma unroll
    for (int c8 = 0; c8 < 8; ++c8) {
        unsigned short tmp[8];
        #pragma unroll
        for (int j = 0; j < 8; ++j) {
            const float* xc = xb + (c8 * 8 + j) * HWSZ;
            float v = w00 * xc[o00] + w01 * xc[o01] + w10 * xc[o10] + w11 * xc[o11];
            tmp[j] = f2bf(v);
        }
        *(uint4*)&outp[c8 * 8] = *(const uint4*)tmp;
    }
}

// ---------------- Kernel 3: bf16 MFMA GEMM  G[m][n] = Wb[m][k] * colT[n][k] --
// 128x128 tile per block, 4 waves (2x2), each wave 64x64 = 4x4 MFMA 16x16x32.
__global__ __launch_bounds__(256) void gemm_kernel(const unsigned short* __restrict__ Wb,
                                                   const unsigned short* __restrict__ colT,
                                                   float* __restrict__ G) {
    __shared__ __align__(16) short As[128 * 32];
    __shared__ __align__(16) short Bs[128 * 32];

    int tid  = threadIdx.x;
    int lane = tid & 63;
    int wv   = tid >> 6;
    int wm   = wv >> 1;           // 0..1
    int wn   = wv & 1;            // 0..1
    int m0   = (blockIdx.x & 1) * 128;
    int n0   = (blockIdx.x >> 1) * 128;

    int erow = tid >> 2;          // 0..63
    int ecol = (tid & 3) * 8;
    const unsigned short* gA = Wb   + (size_t)(m0 + erow) * KT + ecol;
    const unsigned short* gB = colT + (size_t)(n0 + erow) * KT + ecol;
    short* lA = As + tid * 8;
    short* lB = Bs + tid * 8;

    f32x4 acc[4][4] = {};

    int quad = lane >> 4;
    int lrow = lane & 15;

    for (int kt = 0; kt < KT; kt += 32) {
        gl_lds16(gA + kt,            lA);
        gl_lds16(gA + 64 * KT + kt,  lA + 2048);
        gl_lds16(gB + kt,            lB);
        gl_lds16(gB + 64 * KT + kt,  lB + 2048);
        __syncthreads();   // drains vmcnt(0) -> LDS data visible

        short8 a[4], b[4];
        #pragma unroll
        for (int i = 0; i < 4; ++i)
            a[i] = *(const short8*)&As[(wm * 64 + i * 16 + lrow) * 32 + quad * 8];
        #pragma unroll
        for (int j = 0; j < 4; ++j)
            b[j] = *(const short8*)&Bs[(wn * 64 + j * 16 + lrow) * 32 + quad * 8];
        #pragma unroll
        for (int i = 0; i < 4; ++i)
            #pragma unroll
            for (int j = 0; j < 4; ++j)
                acc[i][j] = __builtin_amdgcn_mfma_f32_16x16x32_bf16(a[i], b[j], acc[i][j], 0, 0, 0);
        __syncthreads();   // protect LDS before next stage
    }

    // Epilogue: D[row = quad*4 + r][col = lane&15]
    #pragma unroll
    for (int i = 0; i < 4; ++i) {
        int m = m0 + wm * 64 + i * 16 + quad * 4;
        #pragma unroll
        for (int j = 0; j < 4; ++j) {
            int n = n0 + wn * 64 + j * 16 + lrow;
            #pragma unroll
            for (int r = 0; r < 4; ++r)
                G[(size_t)(m + r) * NND + n] = acc[i][j][r];
        }
    }
}

// ---------------- Kernel 4: GroupNorm stats (mean, rstd) per (b, group) -----
__global__ __launch_bounds__(256) void gn_stats_kernel(const float* __restrict__ G,
                                                       float* __restrict__ stats) {
    int bg = blockIdx.x;          // 0..127
    int b  = bg >> 5;
    int g  = bg & 31;
    float s1 = 0.f, s2 = 0.f;
    #pragma unroll
    for (int o = 0; o < 8; ++o) {
        const float* row = G + (size_t)(g * 8 + o) * NND + b * HWSZ;
        for (int i = threadIdx.x; i < HWSZ; i += 256) {
            float v = row[i];
            s1 += v;
            s2 += v * v;
        }
    }
    #pragma unroll
    for (int off = 1; off < 64; off <<= 1) {
        s1 += __shfl_xor(s1, off);
        s2 += __shfl_xor(s2, off);
    }
    __shared__ float red[8];
    if ((threadIdx.x & 63) == 0) {
        red[(threadIdx.x >> 6) * 2]     = s1;
        red[(threadIdx.x >> 6) * 2 + 1] = s2;
    }
    __syncthreads();
    if (threadIdx.x == 0) {
        float t1 = red[0] + red[2] + red[4] + red[6];
        float t2 = red[1] + red[3] + red[5] + red[7];
        const float invN = 1.f / 32768.f;
        float mean = t1 * invN;
        float var  = t2 * invN - mean * mean;
        stats[bg * 2]     = mean;
        stats[bg * 2 + 1] = rsqrtf(var + EPSV);
    }
}

// ---------------- Kernel 5: GN apply + ReLU, [o][b*hw] -> [b][o][hw] --------
__global__ __launch_bounds__(256) void gn_apply_kernel(const float* __restrict__ G,
                                                       const float* __restrict__ stats,
                                                       const float* __restrict__ gamma,
                                                       const float* __restrict__ beta,
                                                       float* __restrict__ out) {
    int idx = blockIdx.x * 256 + threadIdx.x;   // 1,048,576 float4 groups
    int hw4 = idx & 1023;
    int o   = (idx >> 10) & 255;
    int b   = idx >> 18;
    int g   = o >> 3;
    float mean = stats[(b * 32 + g) * 2];
    float rstd = stats[(b * 32 + g) * 2 + 1];
    float ga = gamma[o], be = beta[o];
    const float4 v = *(const float4*)&G[(size_t)o * NND + b * HWSZ + hw4 * 4];
    float4 r;
    r.x = fmaxf(0.f, (v.x - mean) * rstd * ga + be);
    r.y = fmaxf(0.f, (v.y - mean) * rstd * ga + be);
    r.z = fmaxf(0.f, (v.z - mean) * rstd * ga + be);
    r.w = fmaxf(0.f, (v.w - mean) * rstd * ga + be);
    *(float4*)&out[(size_t)(b * CCH + o) * HWSZ + hw4 * 4] = r;
}

extern "C" void kernel_launch(void* const* d_in, const int* in_sizes, int n_in,
                              void* d_out, int out_size, void* d_ws, size_t ws_size,
                              hipStream_t stream) {
    const float* x     = (const float*)d_in[0];
    const float* shp   = (const float*)d_in[1];
    const float* woff  = (const float*)d_in[2];
    const float* wdef  = (const float*)d_in[3];
    const float* gamma = (const float*)d_in[4];
    const float* beta  = (const float*)d_in[5];
    float* out = (float*)d_out;

    char* ws = (char*)d_ws;
    unsigned short* colT = (unsigned short*)(ws + WS_COLT);
    unsigned short* Wb   = (unsigned short*)(ws + WS_WB);
    float* G             = (float*)(ws + WS_G);
    float* stats         = (float*)(ws + WS_STATS);

    wconv_kernel<<<2304, 256, 0, stream>>>(wdef, Wb);
    col_kernel<<<2304, 256, 0, stream>>>(x, shp, woff, colT);
    gemm_kernel<<<256, 256, 0, stream>>>(Wb, colT, G);
    gn_stats_kernel<<<128, 256, 0, stream>>>(G, stats);
    gn_apply_kernel<<<4096, 256, 0, stream>>>(G, stats, gamma, beta, out);
}

// Round 2
// 229.380 us; speedup vs baseline: 1.1262x; 1.1262x over previous
//
#include <hip/hip_runtime.h>
#include <stdint.h>

// Problem constants
#define BB   4
#define CCH  256
#define HH   64
#define WWD  64
#define HWSZ 4096          // H*W
#define DGRP 4
#define CG   64            // C / DG
#define KKN  9
#define KT   2304          // C * KK  (k index = kk*256 + c)
#define NND  16384         // B*H*W
#define GNG  32
#define EPSV 1e-5f

// Workspace layout (bytes):
//  colT     bf16 [NND][KT]            @ 0          size 75,497,472
//  Wb       bf16 [256][KT]            @ 75497472   size  1,179,648
//  G        f32  [256][NND]           @ 76677120   size 16,777,216
//  stats    f32  [128][2]             @ 93454336   size      1,024
//  partials f32  [1024][2]            @ 93455360   size      8,192
#define WS_COLT  0
#define WS_WB    75497472
#define WS_G     76677120
#define WS_STATS 93454336
#define WS_PART  93455360

typedef __attribute__((ext_vector_type(8))) short short8;
typedef __attribute__((ext_vector_type(4))) float f32x4;

__device__ inline unsigned short f2bf(float f) {
    union { float f; unsigned u; } v; v.f = f;
    unsigned u = v.u;
    return (unsigned short)((u + 0x7FFFu + ((u >> 16) & 1u)) >> 16);  // RNE
}

__device__ inline void gl_lds16(const void* g, void* l) {
    __builtin_amdgcn_global_load_lds(
        (const __attribute__((address_space(1))) void*)g,
        (__attribute__((address_space(3))) void*)l,
        16, 0, 0);
}

// ---------------- Kernel 1: weight repack fp32 -> bf16, k = kk*256 + c ------
__global__ __launch_bounds__(256) void wconv_kernel(const float* __restrict__ wd,
                                                    unsigned short* __restrict__ Wb) {
    int idx = blockIdx.x * 256 + threadIdx.x;       // 589,824 total
    int o = idx / KT;
    int r = idx % KT;
    int kk = r >> 8;        // r / 256
    int c  = r & 255;
    Wb[idx] = f2bf(wd[o * KT + c * KKN + kk]);
}

// ---------------- Kernel 2: offsets + bilinear sampling -> colT bf16 --------
// thread = one (b, dg, kk, c8-group-of-8, h, w); 8 channels per thread.
// 32 independent gather loads in flight per thread -> latency hiding via MLP.
__global__ __launch_bounds__(256) void col_kernel(const float* __restrict__ x,
                                                  const float* __restrict__ shp,
                                                  const float* __restrict__ woff,
                                                  unsigned short* __restrict__ colT) {
    int idx = blockIdx.x * 256 + threadIdx.x;       // 4,718,592 total (18432 blocks)
    int hw  = idx & 4095;
    int w   = idx & 63;
    int h   = (idx >> 6) & 63;
    int rest = idx >> 12;         // 0..1151
    int c8  = rest & 7;           // channel group of 8 within the dg's 64
    int q   = rest >> 3;          // (b*4+dg)*9 + kk,  0..143
    int kk  = q % KKN;
    int bdg = q / KKN;
    int dg  = bdg & 3;
    int b   = bdg >> 2;

    float s0 = shp[(b * 4 + 0) * HWSZ + hw];
    float s1 = shp[(b * 4 + 1) * HWSZ + hw];
    float s2 = shp[(b * 4 + 2) * HWSZ + hw];
    float s3 = shp[(b * 4 + 3) * HWSZ + hw];

    const float* wo = woff + (dg * 18 + kk * 2) * 4;   // rows o_y, o_x back-to-back
    float dy = wo[0] * s0 + wo[1] * s1 + wo[2] * s2 + wo[3] * s3;
    float dx = wo[4] * s0 + wo[5] * s1 + wo[6] * s2 + wo[7] * s3;

    int ky = kk / 3, kx = kk % 3;
    float y  = (float)(h - 1 + ky) + dy;
    float xs = (float)(w - 1 + kx) + dx;
    float y0f = floorf(y), x0f = floorf(xs);
    float wy1 = y - y0f,  wx1 = xs - x0f;
    float wy0 = 1.f - wy1, wx0 = 1.f - wx1;
    int iy0 = (int)y0f, ix0 = (int)x0f;
    int iy1 = iy0 + 1,  ix1 = ix0 + 1;
    bool vy0 = (iy0 >= 0) && (iy0 < HH);
    bool vy1 = (iy1 >= 0) && (iy1 < HH);
    bool vx0 = (ix0 >= 0) && (ix0 < WWD);
    bool vx1 = (ix1 >= 0) && (ix1 < WWD);
    float w00 = (vy0 && vx0) ? wy0 * wx0 : 0.f;
    float w01 = (vy0 && vx1) ? wy0 * wx1 : 0.f;
    float w10 = (vy1 && vx0) ? wy1 * wx0 : 0.f;
    float w11 = (vy1 && vx1) ? wy1 * wx1 : 0.f;
    int cy0 = min(max(iy0, 0), HH - 1);
    int cy1 = min(max(iy1, 0), HH - 1);
    int cx0 = min(max(ix0, 0), WWD - 1);
    int cx1 = min(max(ix1, 0), WWD - 1);
    int o00 = cy0 * WWD + cx0;
    int o01 = cy0 * WWD + cx1;
    int o10 = cy1 * WWD + cx0;
    int o11 = cy1 * WWD + cx1;

    const float* xb = x + (size_t)(b * CCH + dg * CG + c8 * 8) * HWSZ;

    // Issue all 32 gathers before any blend -> maximal loads-in-flight.
    float v00[8], v01[8], v10[8], v11[8];
    #pragma unroll
    for (int j = 0; j < 8; ++j) v00[j] = xb[j * HWSZ + o00];
    #pragma unroll
    for (int j = 0; j < 8; ++j) v01[j] = xb[j * HWSZ + o01];
    #pragma unroll
    for (int j = 0; j < 8; ++j) v10[j] = xb[j * HWSZ + o10];
    #pragma unroll
    for (int j = 0; j < 8; ++j) v11[j] = xb[j * HWSZ + o11];

    unsigned short tmp[8];
    #pragma unroll
    for (int j = 0; j < 8; ++j) {
        float v = w00 * v00[j] + w01 * v01[j] + w10 * v10[j] + w11 * v11[j];
        tmp[j] = f2bf(v);
    }
    unsigned short* outp = colT + (size_t)(b * HWSZ + hw) * KT + kk * 256 + dg * CG + c8 * 8;
    *(uint4*)outp = *(const uint4*)tmp;
}

// ---------------- Kernel 3: bf16 MFMA GEMM  G[m][n] = Wb[m][k] * colT[n][k] --
// 64x128 tile per block (m x n), 4 waves (2x2), each wave 32x64 = 2x4 MFMA
// 16x16x32. 512 blocks -> 2 blocks/CU, 8 waves/CU.
__global__ __launch_bounds__(256) void gemm_kernel(const unsigned short* __restrict__ Wb,
                                                   const unsigned short* __restrict__ colT,
                                                   float* __restrict__ G) {
    __shared__ __align__(16) short As[64 * 32];    // 4 KB
    __shared__ __align__(16) short Bs[128 * 32];   // 8 KB

    int tid  = threadIdx.x;
    int lane = tid & 63;
    int wv   = tid >> 6;
    int wm   = wv >> 1;           // 0..1 -> 32-row slab
    int wn   = wv & 1;            // 0..1 -> 64-col slab
    int m0   = (blockIdx.x & 3) * 64;
    int n0   = (blockIdx.x >> 2) * 128;

    int erow = tid >> 2;          // 0..63
    int ecol = (tid & 3) * 8;
    const unsigned short* gA = Wb   + (size_t)(m0 + erow) * KT + ecol;
    const unsigned short* gB = colT + (size_t)(n0 + erow) * KT + ecol;
    short* lA = As + tid * 8;
    short* lB = Bs + tid * 8;

    f32x4 acc[2][4] = {};

    int quad = lane >> 4;
    int lrow = lane & 15;

    for (int kt = 0; kt < KT; kt += 32) {
        gl_lds16(gA + kt,            lA);
        gl_lds16(gB + kt,            lB);
        gl_lds16(gB + 64 * KT + kt,  lB + 2048);
        __syncthreads();   // drains vmcnt(0) -> LDS data visible

        short8 a[2], b[4];
        #pragma unroll
        for (int i = 0; i < 2; ++i)
            a[i] = *(const short8*)&As[(wm * 32 + i * 16 + lrow) * 32 + quad * 8];
        #pragma unroll
        for (int j = 0; j < 4; ++j)
            b[j] = *(const short8*)&Bs[(wn * 64 + j * 16 + lrow) * 32 + quad * 8];
        #pragma unroll
        for (int i = 0; i < 2; ++i)
            #pragma unroll
            for (int j = 0; j < 4; ++j)
                acc[i][j] = __builtin_amdgcn_mfma_f32_16x16x32_bf16(a[i], b[j], acc[i][j], 0, 0, 0);
        __syncthreads();   // protect LDS before next stage
    }

    // Epilogue: D[row = quad*4 + r][col = lane&15]
    #pragma unroll
    for (int i = 0; i < 2; ++i) {
        int m = m0 + wm * 32 + i * 16 + quad * 4;
        #pragma unroll
        for (int j = 0; j < 4; ++j) {
            int n = n0 + wn * 64 + j * 16 + lrow;
            #pragma unroll
            for (int r = 0; r < 4; ++r)
                G[(size_t)(m + r) * NND + n] = acc[i][j][r];
        }
    }
}

// ---------------- Kernel 4a: GN partial sums, one block per (b,g,o) channel --
__global__ __launch_bounds__(256) void gn_part_kernel(const float* __restrict__ G,
                                                      float* __restrict__ partials) {
    int blk = blockIdx.x;         // 0..1023 = bg*8 + o
    int bg  = blk >> 3;
    int o   = blk & 7;
    int b   = bg >> 5;
    int g   = bg & 31;
    const float* row = G + (size_t)(g * 8 + o) * NND + b * HWSZ;
    float s1 = 0.f, s2 = 0.f;
    #pragma unroll
    for (int it = 0; it < 16; ++it) {
        float v = row[it * 256 + threadIdx.x];
        s1 += v;
        s2 += v * v;
    }
    #pragma unroll
    for (int off = 1; off < 64; off <<= 1) {
        s1 += __shfl_xor(s1, off);
        s2 += __shfl_xor(s2, off);
    }
    __shared__ float red[8];
    if ((threadIdx.x & 63) == 0) {
        red[(threadIdx.x >> 6) * 2]     = s1;
        red[(threadIdx.x >> 6) * 2 + 1] = s2;
    }
    __syncthreads();
    if (threadIdx.x == 0) {
        partials[blk * 2]     = red[0] + red[2] + red[4] + red[6];
        partials[blk * 2 + 1] = red[1] + red[3] + red[5] + red[7];
    }
}

// ---------------- Kernel 4b: finalize mean/rstd per (b, group) --------------
__global__ __launch_bounds__(128) void gn_stats_kernel(const float* __restrict__ partials,
                                                       float* __restrict__ stats) {
    int bg = threadIdx.x;         // 0..127
    float t1 = 0.f, t2 = 0.f;
    #pragma unroll
    for (int o = 0; o < 8; ++o) {
        t1 += partials[(bg * 8 + o) * 2];
        t2 += partials[(bg * 8 + o) * 2 + 1];
    }
    const float invN = 1.f / 32768.f;
    float mean = t1 * invN;
    float var  = t2 * invN - mean * mean;
    stats[bg * 2]     = mean;
    stats[bg * 2 + 1] = rsqrtf(var + EPSV);
}

// ---------------- Kernel 5: GN apply + ReLU, [o][b*hw] -> [b][o][hw] --------
__global__ __launch_bounds__(256) void gn_apply_kernel(const float* __restrict__ G,
                                                       const float* __restrict__ stats,
                                                       const float* __restrict__ gamma,
                                                       const float* __restrict__ beta,
                                                       float* __restrict__ out) {
    int idx = blockIdx.x * 256 + threadIdx.x;   // 1,048,576 float4 groups
    int hw4 = idx & 1023;
    int o   = (idx >> 10) & 255;
    int b   = idx >> 18;
    int g   = o >> 3;
    float mean = stats[(b * 32 + g) * 2];
    float rstd = stats[(b * 32 + g) * 2 + 1];
    float ga = gamma[o], be = beta[o];
    const float4 v = *(const float4*)&G[(size_t)o * NND + b * HWSZ + hw4 * 4];
    float4 r;
    r.x = fmaxf(0.f, (v.x - mean) * rstd * ga + be);
    r.y = fmaxf(0.f, (v.y - mean) * rstd * ga + be);
    r.z = fmaxf(0.f, (v.z - mean) * rstd * ga + be);
    r.w = fmaxf(0.f, (v.w - mean) * rstd * ga + be);
    *(float4*)&out[(size_t)(b * CCH + o) * HWSZ + hw4 * 4] = r;
}

extern "C" void kernel_launch(void* const* d_in, const int* in_sizes, int n_in,
                              void* d_out, int out_size, void* d_ws, size_t ws_size,
                              hipStream_t stream) {
    const float* x     = (const float*)d_in[0];
    const float* shp   = (const float*)d_in[1];
    const float* woff  = (const float*)d_in[2];
    const float* wdef  = (const float*)d_in[3];
    const float* gamma = (const float*)d_in[4];
    const float* beta  = (const float*)d_in[5];
    float* out = (float*)d_out;

    char* ws = (char*)d_ws;
    unsigned short* colT = (unsigned short*)(ws + WS_COLT);
    unsigned short* Wb   = (unsigned short*)(ws + WS_WB);
    float* G             = (float*)(ws + WS_G);
    float* stats         = (float*)(ws + WS_STATS);
    float* partials      = (float*)(ws + WS_PART);

    wconv_kernel<<<2304, 256, 0, stream>>>(wdef, Wb);
    col_kernel<<<18432, 256, 0, stream>>>(x, shp, woff, colT);
    gemm_kernel<<<512, 256, 0, stream>>>(Wb, colT, G);
    gn_part_kernel<<<1024, 256, 0, stream>>>(G, partials);
    gn_stats_kernel<<<1, 128, 0, stream>>>(partials, stats);
    gn_apply_kernel<<<4096, 256, 0, stream>>>(G, stats, gamma, beta, out);
}

// Round 3
// 164.518 us; speedup vs baseline: 1.5703x; 1.3943x over previous
//
#include <hip/hip_runtime.h>
#include <stdint.h>

// Problem constants
#define BB   4
#define CCH  256
#define HH   64
#define WWD  64
#define HWSZ 4096          // H*W
#define DGRP 4
#define CG   64            // C / DG
#define KKN  9
#define KT   2304          // C * KK  (k index = kk*256 + c)
#define NND  16384         // B*H*W
#define GNG  32
#define EPSV 1e-5f

// Workspace layout (bytes):
//  colT     bf16 [NND][KT]            @ 0          size 75,497,472
//  Wb       bf16 [256][KT]            @ 75497472   size  1,179,648
//  G        f32  [256][NND]           @ 76677120   size 16,777,216
//  stats    f32  [128][2]             @ 93454336   size      1,024
//  partials f32  [1024][2]            @ 93455360   size      8,192
#define WS_COLT  0
#define WS_WB    75497472
#define WS_G     76677120
#define WS_STATS 93454336
#define WS_PART  93455360

typedef __attribute__((ext_vector_type(8))) short short8;
typedef __attribute__((ext_vector_type(4))) float f32x4;

__device__ inline unsigned short f2bf(float f) {
    union { float f; unsigned u; } v; v.f = f;
    unsigned u = v.u;
    return (unsigned short)((u + 0x7FFFu + ((u >> 16) & 1u)) >> 16);  // RNE
}

__device__ inline void gl_lds16(const void* g, void* l) {
    __builtin_amdgcn_global_load_lds(
        (const __attribute__((address_space(1))) void*)g,
        (__attribute__((address_space(3))) void*)l,
        16, 0, 0);
}

// ---------------- Kernel 1: weight repack fp32 -> bf16, k = kk*256 + c ------
__global__ __launch_bounds__(256) void wconv_kernel(const float* __restrict__ wd,
                                                    unsigned short* __restrict__ Wb) {
    int idx = blockIdx.x * 256 + threadIdx.x;       // 589,824 total
    int o = idx / KT;
    int r = idx % KT;
    int kk = r >> 8;        // r / 256
    int c  = r & 255;
    Wb[idx] = f2bf(wd[o * KT + c * KKN + kk]);
}

// ---------------- Kernel 2: LDS-tiled bilinear sampling -> colT bf16 --------
// Block = (b, dg, chalf of 32 ch, 4-row band). x slab (32ch x 8rows x 64w,
// channel-interleaved-by-4) staged in 64KB LDS; all 4 bilinear corners are
// ds_read_b128 (4 ch/lane, lane stride 16B -> conflict-free b128). Each lane
// owns a contiguous 64B colT chunk -> 4x dwordx4 full-line stores.
__global__ __launch_bounds__(256) void col_kernel(const float* __restrict__ x,
                                                  const float* __restrict__ shp,
                                                  const float* __restrict__ woff,
                                                  unsigned short* __restrict__ colT) {
    __shared__ __align__(16) float xt[8 * 8 * 64 * 4];   // [c4g][row][w][c4] = 64KB

    int bid   = blockIdx.x;          // 512 blocks
    int band  = bid & 15;
    int chalf = (bid >> 4) & 1;
    int dg    = (bid >> 5) & 3;
    int b     = bid >> 7;
    int h0    = band * 4;
    int tid   = threadIdx.x;
    int lane  = tid & 63;            // = w in compute phase
    int wv    = tid >> 6;            // wave -> row of the band

    // ---- stage x slab: 16384 floats, coalesced global, batched 8 for MLP ----
    const float* xg = x + (size_t)(b * CCH + dg * CG + chalf * 32) * HWSZ;
    #pragma unroll 1
    for (int ii = 0; ii < 8; ++ii) {
        float v[8]; int la[8];
        #pragma unroll
        for (int u = 0; u < 8; ++u) {
            int idx = (ii * 8 + u) * 256 + tid;
            int w = idx & 63;
            int r = (idx >> 6) & 7;
            int j = idx >> 9;                       // channel 0..31
            int gr = min(max(h0 - 2 + r, 0), HH - 1);
            v[u]  = xg[(size_t)j * HWSZ + gr * 64 + w];
            la[u] = ((j >> 2) * 8 + r) * 256 + w * 4 + (j & 3);   // dword index
        }
        #pragma unroll
        for (int u = 0; u < 8; ++u) xt[la[u]] = v[u];
    }
    __syncthreads();

    // ---- compute: wave wv handles row h0+wv, loops kk=0..8 ----
    int h  = h0 + wv;
    int hw = h * 64 + lane;
    float s0 = shp[(b * 4 + 0) * HWSZ + hw];
    float s1 = shp[(b * 4 + 1) * HWSZ + hw];
    float s2 = shp[(b * 4 + 2) * HWSZ + hw];
    float s3 = shp[(b * 4 + 3) * HWSZ + hw];

    unsigned short* rowp = colT + (size_t)(b * HWSZ + hw) * KT + dg * CG + chalf * 32;
    const char* xtb = (const char*)xt;

    #pragma unroll
    for (int kk = 0; kk < KKN; ++kk) {
        const float* wo = woff + (dg * 18 + kk * 2) * 4;
        float dy = wo[0] * s0 + wo[1] * s1 + wo[2] * s2 + wo[3] * s3;
        float dx = wo[4] * s0 + wo[5] * s1 + wo[6] * s2 + wo[7] * s3;

        int ky = kk / 3, kx = kk % 3;
        float y  = (float)(h - 1 + ky) + dy;
        float xs = (float)(lane - 1 + kx) + dx;
        float y0f = floorf(y), x0f = floorf(xs);
        float wy1 = y - y0f,  wx1 = xs - x0f;
        float wy0 = 1.f - wy1, wx0 = 1.f - wx1;
        int iy0 = (int)y0f, ix0 = (int)x0f;
        int iy1 = iy0 + 1,  ix1 = ix0 + 1;
        bool vy0 = (iy0 >= 0) && (iy0 < HH);
        bool vy1 = (iy1 >= 0) && (iy1 < HH);
        bool vx0 = (ix0 >= 0) && (ix0 < WWD);
        bool vx1 = (ix1 >= 0) && (ix1 < WWD);
        float w00 = (vy0 && vx0) ? wy0 * wx0 : 0.f;
        float w01 = (vy0 && vx1) ? wy0 * wx1 : 0.f;
        float w10 = (vy1 && vx0) ? wy1 * wx0 : 0.f;
        float w11 = (vy1 && vx1) ? wy1 * wx1 : 0.f;
        int cy0 = min(max(iy0, 0), HH - 1);
        int cy1 = min(max(iy1, 0), HH - 1);
        int cx0 = min(max(ix0, 0), WWD - 1);
        int cx1 = min(max(ix1, 0), WWD - 1);
        // tile row indices (global row - (h0-2)); clamp is safety for huge offsets
        int ty0 = min(max(cy0 - (h0 - 2), 0), 7);
        int ty1 = min(max(cy1 - (h0 - 2), 0), 7);
        int a00 = (ty0 * 64 + cx0) * 16;
        int a01 = (ty0 * 64 + cx1) * 16;
        int a10 = (ty1 * 64 + cx0) * 16;
        int a11 = (ty1 * 64 + cx1) * 16;

        unsigned short tmp[32];
        #pragma unroll
        for (int c4g = 0; c4g < 8; ++c4g) {
            int base = c4g * 8192;
            const float4 v00 = *(const float4*)(xtb + base + a00);
            const float4 v01 = *(const float4*)(xtb + base + a01);
            const float4 v10 = *(const float4*)(xtb + base + a10);
            const float4 v11 = *(const float4*)(xtb + base + a11);
            float rx = w00 * v00.x + w01 * v01.x + w10 * v10.x + w11 * v11.x;
            float ry = w00 * v00.y + w01 * v01.y + w10 * v10.y + w11 * v11.y;
            float rz = w00 * v00.z + w01 * v01.z + w10 * v10.z + w11 * v11.z;
            float rw = w00 * v00.w + w01 * v01.w + w10 * v10.w + w11 * v11.w;
            tmp[c4g * 4 + 0] = f2bf(rx);
            tmp[c4g * 4 + 1] = f2bf(ry);
            tmp[c4g * 4 + 2] = f2bf(rz);
            tmp[c4g * 4 + 3] = f2bf(rw);
        }
        uint4* dst = (uint4*)(rowp + kk * 256);
        const uint4* src = (const uint4*)tmp;
        dst[0] = src[0];
        dst[1] = src[1];
        dst[2] = src[2];
        dst[3] = src[3];
    }
}

// ---------------- Kernel 3: bf16 MFMA GEMM  G[m][n] = Wb[m][k] * colT[n][k] --
// 64x128 tile per block (m x n), 4 waves (2x2), each wave 32x64 = 2x4 MFMA
// 16x16x32. 512 blocks -> 2 blocks/CU, 8 waves/CU.
__global__ __launch_bounds__(256) void gemm_kernel(const unsigned short* __restrict__ Wb,
                                                   const unsigned short* __restrict__ colT,
                                                   float* __restrict__ G) {
    __shared__ __align__(16) short As[64 * 32];    // 4 KB
    __shared__ __align__(16) short Bs[128 * 32];   // 8 KB

    int tid  = threadIdx.x;
    int lane = tid & 63;
    int wv   = tid >> 6;
    int wm   = wv >> 1;           // 0..1 -> 32-row slab
    int wn   = wv & 1;            // 0..1 -> 64-col slab
    int m0   = (blockIdx.x & 3) * 64;
    int n0   = (blockIdx.x >> 2) * 128;

    int erow = tid >> 2;          // 0..63
    int ecol = (tid & 3) * 8;
    const unsigned short* gA = Wb   + (size_t)(m0 + erow) * KT + ecol;
    const unsigned short* gB = colT + (size_t)(n0 + erow) * KT + ecol;
    short* lA = As + tid * 8;
    short* lB = Bs + tid * 8;

    f32x4 acc[2][4] = {};

    int quad = lane >> 4;
    int lrow = lane & 15;

    for (int kt = 0; kt < KT; kt += 32) {
        gl_lds16(gA + kt,            lA);
        gl_lds16(gB + kt,            lB);
        gl_lds16(gB + 64 * KT + kt,  lB + 2048);
        __syncthreads();   // drains vmcnt(0) -> LDS data visible

        short8 a[2], b[4];
        #pragma unroll
        for (int i = 0; i < 2; ++i)
            a[i] = *(const short8*)&As[(wm * 32 + i * 16 + lrow) * 32 + quad * 8];
        #pragma unroll
        for (int j = 0; j < 4; ++j)
            b[j] = *(const short8*)&Bs[(wn * 64 + j * 16 + lrow) * 32 + quad * 8];
        #pragma unroll
        for (int i = 0; i < 2; ++i)
            #pragma unroll
            for (int j = 0; j < 4; ++j)
                acc[i][j] = __builtin_amdgcn_mfma_f32_16x16x32_bf16(a[i], b[j], acc[i][j], 0, 0, 0);
        __syncthreads();   // protect LDS before next stage
    }

    // Epilogue: D[row = quad*4 + r][col = lane&15]
    #pragma unroll
    for (int i = 0; i < 2; ++i) {
        int m = m0 + wm * 32 + i * 16 + quad * 4;
        #pragma unroll
        for (int j = 0; j < 4; ++j) {
            int n = n0 + wn * 64 + j * 16 + lrow;
            #pragma unroll
            for (int r = 0; r < 4; ++r)
                G[(size_t)(m + r) * NND + n] = acc[i][j][r];
        }
    }
}

// ---------------- Kernel 4a: GN partial sums, one block per (b,g,o) channel --
__global__ __launch_bounds__(256) void gn_part_kernel(const float* __restrict__ G,
                                                      float* __restrict__ partials) {
    int blk = blockIdx.x;         // 0..1023 = bg*8 + o
    int bg  = blk >> 3;
    int o   = blk & 7;
    int b   = bg >> 5;
    int g   = bg & 31;
    const float* row = G + (size_t)(g * 8 + o) * NND + b * HWSZ;
    float s1 = 0.f, s2 = 0.f;
    #pragma unroll
    for (int it = 0; it < 16; ++it) {
        float v = row[it * 256 + threadIdx.x];
        s1 += v;
        s2 += v * v;
    }
    #pragma unroll
    for (int off = 1; off < 64; off <<= 1) {
        s1 += __shfl_xor(s1, off);
        s2 += __shfl_xor(s2, off);
    }
    __shared__ float red[8];
    if ((threadIdx.x & 63) == 0) {
        red[(threadIdx.x >> 6) * 2]     = s1;
        red[(threadIdx.x >> 6) * 2 + 1] = s2;
    }
    __syncthreads();
    if (threadIdx.x == 0) {
        partials[blk * 2]     = red[0] + red[2] + red[4] + red[6];
        partials[blk * 2 + 1] = red[1] + red[3] + red[5] + red[7];
    }
}

// ---------------- Kernel 4b: finalize mean/rstd per (b, group) --------------
__global__ __launch_bounds__(128) void gn_stats_kernel(const float* __restrict__ partials,
                                                       float* __restrict__ stats) {
    int bg = threadIdx.x;         // 0..127
    float t1 = 0.f, t2 = 0.f;
    #pragma unroll
    for (int o = 0; o < 8; ++o) {
        t1 += partials[(bg * 8 + o) * 2];
        t2 += partials[(bg * 8 + o) * 2 + 1];
    }
    const float invN = 1.f / 32768.f;
    float mean = t1 * invN;
    float var  = t2 * invN - mean * mean;
    stats[bg * 2]     = mean;
    stats[bg * 2 + 1] = rsqrtf(var + EPSV);
}

// ---------------- Kernel 5: GN apply + ReLU, [o][b*hw] -> [b][o][hw] --------
__global__ __launch_bounds__(256) void gn_apply_kernel(const float* __restrict__ G,
                                                       const float* __restrict__ stats,
                                                       const float* __restrict__ gamma,
                                                       const float* __restrict__ beta,
                                                       float* __restrict__ out) {
    int idx = blockIdx.x * 256 + threadIdx.x;   // 1,048,576 float4 groups
    int hw4 = idx & 1023;
    int o   = (idx >> 10) & 255;
    int b   = idx >> 18;
    int g   = o >> 3;
    float mean = stats[(b * 32 + g) * 2];
    float rstd = stats[(b * 32 + g) * 2 + 1];
    float ga = gamma[o], be = beta[o];
    const float4 v = *(const float4*)&G[(size_t)o * NND + b * HWSZ + hw4 * 4];
    float4 r;
    r.x = fmaxf(0.f, (v.x - mean) * rstd * ga + be);
    r.y = fmaxf(0.f, (v.y - mean) * rstd * ga + be);
    r.z = fmaxf(0.f, (v.z - mean) * rstd * ga + be);
    r.w = fmaxf(0.f, (v.w - mean) * rstd * ga + be);
    *(float4*)&out[(size_t)(b * CCH + o) * HWSZ + hw4 * 4] = r;
}

extern "C" void kernel_launch(void* const* d_in, const int* in_sizes, int n_in,
                              void* d_out, int out_size, void* d_ws, size_t ws_size,
                              hipStream_t stream) {
    const float* x     = (const float*)d_in[0];
    const float* shp   = (const float*)d_in[1];
    const float* woff  = (const float*)d_in[2];
    const float* wdef  = (const float*)d_in[3];
    const float* gamma = (const float*)d_in[4];
    const float* beta  = (const float*)d_in[5];
    float* out = (float*)d_out;

    char* ws = (char*)d_ws;
    unsigned short* colT = (unsigned short*)(ws + WS_COLT);
    unsigned short* Wb   = (unsigned short*)(ws + WS_WB);
    float* G             = (float*)(ws + WS_G);
    float* stats         = (float*)(ws + WS_STATS);
    float* partials      = (float*)(ws + WS_PART);

    wconv_kernel<<<2304, 256, 0, stream>>>(wdef, Wb);
    col_kernel<<<512, 256, 0, stream>>>(x, shp, woff, colT);
    gemm_kernel<<<512, 256, 0, stream>>>(Wb, colT, G);
    gn_part_kernel<<<1024, 256, 0, stream>>>(G, partials);
    gn_stats_kernel<<<1, 128, 0, stream>>>(partials, stats);
    gn_apply_kernel<<<4096, 256, 0, stream>>>(G, stats, gamma, beta, out);
}